// Round 13
// baseline (367.052 us; speedup 1.0000x reference)
//
#include <hip/hip_runtime.h>
#include <hip/hip_fp16.h>

#define NFEAT_IN 21
#define NHID 16
#define NOUT 6
#define BSHIFT 9
#define BW (1 << BSHIFT)     // 512 nodes per bucket
#define NB 512               // bucket array size (supports n <= 262144)
#define PB 256
#define EPT 32
#define CHUNK (PB * EPT)     // 8192 edges per partition block

typedef unsigned int u32x4 __attribute__((ext_vector_type(4)));

// static arenas: bucket b's region starts at b*cap
__global__ void k_init_bcur(int* __restrict__ bcur, int cap) {
    int b = blockIdx.x * blockDim.x + threadIdx.x;
    if (b < NB) bcur[b] = b * cap;
}

// LDS-local bucket sort per 8192-edge chunk, then COALESCED emission.
// Round-12 change: ONE LDS atomic per edge — the histogram atomic's return
// value IS the local rank. Pack (dst<<13)|rank into ebd (dst<2^18, rank<2^13
// -> 31 bits; 0xFFFFFFFF stays unambiguous). Pass 2 places sidx atomic-free.
__global__ __launch_bounds__(256) void
k_partition(const int* __restrict__ src, const int* __restrict__ dst,
            int* __restrict__ bcur, unsigned int* __restrict__ bucketed,
            int cap, int ne) {
    __shared__ unsigned int ebd[CHUNK];     // (dst<<13)|rank; 0xFFFFFFFF invalid
    __shared__ unsigned short sidx[CHUNK];  // bucket-sorted pos -> chunk idx
    __shared__ int lcnt[NB], lstart[NB], lbase[NB];
    __shared__ int s[PB];
    __shared__ int sh_total;
    int t = threadIdx.x;
    long base = (long)blockIdx.x * CHUNK;
    for (int b = t; b < NB; b += PB) lcnt[b] = 0;
    __syncthreads();
    // pass 1: read dst; 1 atomic/edge captures count AND rank
#pragma unroll
    for (int k = 0; k < EPT; k++) {
        int idx = t + k * PB;
        long e = base + idx;
        unsigned int v = 0xFFFFFFFFu;
        if (e < ne) {
            unsigned int d = (unsigned int)dst[e];
            int r = atomicAdd(&lcnt[d >> BSHIFT], 1);
            v = (d << 13) | (unsigned int)r;
        }
        ebd[idx] = v;
    }
    __syncthreads();
    // exclusive scan of 512 bins with 256 threads (2/thread) + reserve global
    int v0 = lcnt[2 * t], v1 = lcnt[2 * t + 1];
    int pair = v0 + v1;
    s[t] = pair;
    __syncthreads();
    for (int off = 1; off < PB; off <<= 1) {
        int tv = (t >= off) ? s[t - off] : 0;
        __syncthreads();
        s[t] += tv;
        __syncthreads();
    }
    int ex = s[t] - pair;
    lstart[2 * t] = ex;
    lstart[2 * t + 1] = ex + v0;
    if (v0 > 0) lbase[2 * t]     = atomicAdd(&bcur[2 * t],     v0);
    if (v1 > 0) lbase[2 * t + 1] = atomicAdd(&bcur[2 * t + 1], v1);
    if (t == PB - 1) sh_total = s[PB - 1];
    __syncthreads();
    // pass 2: place each edge at its sorted slot — NO atomics
#pragma unroll
    for (int k = 0; k < EPT; k++) {
        int idx = t + k * PB;
        unsigned int v = ebd[idx];
        if (v != 0xFFFFFFFFu) {
            unsigned int d = v >> 13;
            unsigned int r = v & 8191u;
            sidx[lstart[d >> BSHIFT] + r] = (unsigned short)idx;
        }
    }
    __syncthreads();
    int total = sh_total;
    // pass 3: coalesced emission (consecutive j -> consecutive gpos in-run)
#pragma unroll
    for (int k = 0; k < EPT; k++) {
        int j = t + k * PB;
        if (j < total) {
            int idx = sidx[j];
            unsigned int d = ebd[idx] >> 13;
            int b = d >> BSHIFT;
            long gpos = (long)lbase[b] + (j - lstart[b]);
            int s_ = src[base + idx];
            if (gpos < (long)(b + 1) * cap)   // arena overflow guard (~12 sigma)
                bucketed[gpos] = ((unsigned int)s_ << BSHIFT) | (d & (BW - 1));
        }
    }
}

// counts + exclusive scan over <=512 buckets (1 block, 512 threads)
__global__ __launch_bounds__(512) void
k_cnt_scan(const int* __restrict__ bcur, int cap, int* __restrict__ cnt,
           int* __restrict__ csr_boff, int nb) {
    __shared__ int s[512];
    int t = threadIdx.x;
    int c = (t < nb) ? (bcur[t] - t * cap) : 0;
    s[t] = c;
    __syncthreads();
    for (int off = 1; off < 512; off <<= 1) {
        int tv = (t >= off) ? s[t - off] : 0;
        __syncthreads();
        s[t] += tv;
        __syncthreads();
    }
    if (t < nb) { cnt[t] = c; csr_boff[t] = s[t] - c; }
}

// Counting-sort each bucket by dst_local -> exact dst-sorted CSR.
// At the 2-LDS-atomic/edge floor — do not touch.
__global__ __launch_bounds__(512) void
k_sort(const unsigned int* __restrict__ bucketed, int cap,
       const int* __restrict__ cnt, const int* __restrict__ csr_boff,
       int* __restrict__ csr_src, int* __restrict__ node_off,
       float* __restrict__ dinv, int n, int ne, int nb) {
    __shared__ int bin[BW], sc[BW], bcur_l[BW];
    int b = blockIdx.x, t = threadIdx.x;
    bin[t] = 0;
    __syncthreads();
    size_t s0r = (size_t)b * cap;
    int c = cnt[b], s0c = csr_boff[b];
    for (int j = t; j < c; j += 512) atomicAdd(&bin[bucketed[s0r + j] & (BW - 1)], 1);
    __syncthreads();
    sc[t] = bin[t];
    __syncthreads();
    for (int off = 1; off < BW; off <<= 1) {
        int v = (t >= off) ? sc[t - off] : 0;
        __syncthreads();
        sc[t] += v;
        __syncthreads();
    }
    {
        int ex = sc[t] - bin[t];            // exclusive prefix
        bcur_l[t] = s0c + ex;
        node_off[(b << BSHIFT) + t] = s0c + ex;
        int node = (b << BSHIFT) + t;
        if (node < n) dinv[node] = rsqrtf((float)bin[t] + 1.0f);
    }
    if (b == 0 && t == 0) node_off[(size_t)nb << BSHIFT] = ne;  // sentinel
    __syncthreads();
    for (int j = t; j < c; j += 512) {
        unsigned int e = bucketed[s0r + j];
        int pos = atomicAdd(&bcur_l[e & (BW - 1)], 1);
        csr_src[pos] = (int)(e >> BSHIFT);
    }
}

// hs1h = fp16((x @ W1) * dinv[i]) — 16 halves (32B) per node
__global__ void k_dense1(const float* __restrict__ x, const float* __restrict__ W1,
                         const float* __restrict__ dinv, __half2* __restrict__ hs1h, int n) {
    __shared__ float sW[NFEAT_IN * NHID];
    for (int t = threadIdx.x; t < NFEAT_IN * NHID; t += blockDim.x) sW[t] = W1[t];
    __syncthreads();
    int i = blockIdx.x * blockDim.x + threadIdx.x;
    if (i >= n) return;
    float xi[NFEAT_IN];
#pragma unroll
    for (int k = 0; k < NFEAT_IN; k++) xi[k] = x[(size_t)i * NFEAT_IN + k];
    float di = dinv[i];
    float r[NHID];
#pragma unroll
    for (int j = 0; j < NHID; j++) {
        float acc = 0.f;
#pragma unroll
        for (int k = 0; k < NFEAT_IN; k++) acc += xi[k] * sW[k * NHID + j];
        r[j] = acc * di;
    }
    __half2* hp = hs1h + (size_t)i * 8;
#pragma unroll
    for (int q = 0; q < 8; q++) hp[q] = __floats2half2_rn(r[2 * q], r[2 * q + 1]);
}

__device__ __forceinline__ void addh16(float* acc, u32x4 u0, u32x4 u1) {
    unsigned int us[8] = {u0[0], u0[1], u0[2], u0[3], u1[0], u1[1], u1[2], u1[3]};
#pragma unroll
    for (int q = 0; q < 8; q++) {
        float2 f = __half22float2(*(const __half2*)&us[q]);
        acc[2 * q] += f.x;
        acc[2 * q + 1] += f.y;
    }
}

// CSR aggregate layer1 + relu + dense2 — 4 THREADS PER NODE.
// Round-12 finding: dur == FETCH / 3.05 TB/s — at the sustained random-line
// gather throughput limit (rate pinned ~3.0-3.1 TB/s across 2x/4x occupancy).
// Structural floor for this op; do not touch further.
__global__ __launch_bounds__(256) void
k_agg1(const int* __restrict__ csr_src, const int* __restrict__ node_off,
       const __half2* __restrict__ hs1h, const float* __restrict__ b1,
       const float* __restrict__ W2, const float* __restrict__ dinv,
       __half2* __restrict__ hs2h, int n) {
    __shared__ float sW[NHID * NOUT];
    __shared__ float sb[NHID];
    __shared__ float lacc[3][64][NHID + 1];
    int t = threadIdx.x;
    if (t < NHID * NOUT) sW[t] = W2[t];
    if (t < NHID) sb[t] = b1[t];
    int tl = t & 63;
    int seg = t >> 6;            // 0..3
    int i = (blockIdx.x << 6) + tl;
    bool active = (i < n);
    int beg = 0, end = 0;
    if (active) {
        int b0 = node_off[i], e0 = node_off[i + 1];
        int len = e0 - b0;
        beg = b0 + (len * seg) / 4;
        end = b0 + (len * (seg + 1)) / 4;
    }
    const u32x4* hb = (const u32x4*)hs1h;
    float acc[NHID];
#pragma unroll
    for (int k = 0; k < NHID; k++) acc[k] = 0.f;
    if (active && seg == 0) {   // self contribution (self-loop: A+I)
        u32x4 u0 = hb[(size_t)i * 2], u1 = hb[(size_t)i * 2 + 1];
        unsigned int us[8] = {u0[0], u0[1], u0[2], u0[3], u1[0], u1[1], u1[2], u1[3]};
#pragma unroll
        for (int q = 0; q < 8; q++) {
            float2 f = __half22float2(*(const __half2*)&us[q]);
            acc[2 * q] = f.x;
            acc[2 * q + 1] = f.y;
        }
    }
    int j = beg;
    for (; j + 4 <= end; j += 4) {
        int s0_ = csr_src[j], s1_ = csr_src[j + 1];
        int s2_ = csr_src[j + 2], s3_ = csr_src[j + 3];
        u32x4 a0 = hb[(size_t)s0_ * 2], a1 = hb[(size_t)s0_ * 2 + 1];
        u32x4 b0 = hb[(size_t)s1_ * 2], b1v = hb[(size_t)s1_ * 2 + 1];
        u32x4 c0 = hb[(size_t)s2_ * 2], c1 = hb[(size_t)s2_ * 2 + 1];
        u32x4 d0 = hb[(size_t)s3_ * 2], d1 = hb[(size_t)s3_ * 2 + 1];
        addh16(acc, a0, a1);
        addh16(acc, b0, b1v);
        addh16(acc, c0, c1);
        addh16(acc, d0, d1);
    }
    for (; j < end; j++) {
        int s_ = csr_src[j];
        addh16(acc, hb[(size_t)s_ * 2], hb[(size_t)s_ * 2 + 1]);
    }
    if (seg != 0) {
#pragma unroll
        for (int k = 0; k < NHID; k++) lacc[seg - 1][tl][k] = acc[k];
    }
    __syncthreads();
    if (seg != 0 || !active) return;
#pragma unroll
    for (int k = 0; k < NHID; k++)
        acc[k] += lacc[0][tl][k] + lacc[1][tl][k] + lacc[2][tl][k];
    float di = dinv[i];
    float z[NHID];
#pragma unroll
    for (int k = 0; k < NHID; k++) z[k] = fmaxf(acc[k] * di + sb[k], 0.0f);
    float h[8];
#pragma unroll
    for (int kk = 0; kk < NOUT; kk++) {
        float s = 0.f;
#pragma unroll
        for (int jj = 0; jj < NHID; jj++) s += z[jj] * sW[jj * NOUT + kk];
        h[kk] = s * di;
    }
    h[6] = 0.f; h[7] = 0.f;
    __half2* op = hs2h + (size_t)i * 4;
#pragma unroll
    for (int q = 0; q < 4; q++) op[q] = __floats2half2_rn(h[2 * q], h[2 * q + 1]);
}

// CSR aggregate layer2 + bias + log_softmax — 2 THREADS PER NODE
__global__ __launch_bounds__(256) void
k_agg2(const int* __restrict__ csr_src, const int* __restrict__ node_off,
       const __half2* __restrict__ hs2h, const float* __restrict__ b2,
       const float* __restrict__ dinv, float* __restrict__ out, int n) {
    __shared__ float sb[NOUT];
    __shared__ float lacc[128][NOUT + 1];
    int t = threadIdx.x;
    if (t < NOUT) sb[t] = b2[t];
    int tl = t & 127;
    bool lo = (t < 128);
    int i = (blockIdx.x << 7) + tl;
    bool active = (i < n);
    int beg = 0, end = 0;
    if (active) {
        int b0 = node_off[i], e0 = node_off[i + 1];
        int h = (e0 - b0 + 1) >> 1;
        beg = lo ? b0 : b0 + h;
        end = lo ? b0 + h : e0;
    }
    const u32x4* hb = (const u32x4*)hs2h;
    float acc[NOUT];
#pragma unroll
    for (int k = 0; k < NOUT; k++) acc[k] = 0.f;
    if (active && lo) {   // self
        u32x4 u = hb[(size_t)i];
        unsigned int us[3] = {u[0], u[1], u[2]};
#pragma unroll
        for (int q = 0; q < 3; q++) {
            float2 f = __half22float2(*(const __half2*)&us[q]);
            acc[2 * q] = f.x;
            acc[2 * q + 1] = f.y;
        }
    }
    int j = beg;
    for (; j + 8 <= end; j += 8) {
        int sid[8];
#pragma unroll
        for (int q = 0; q < 8; q++) sid[q] = csr_src[j + q];
        u32x4 u[8];
#pragma unroll
        for (int q = 0; q < 8; q++) u[q] = hb[(size_t)sid[q]];
#pragma unroll
        for (int q = 0; q < 8; q++) {
            unsigned int us[3] = {u[q][0], u[q][1], u[q][2]};
#pragma unroll
            for (int w = 0; w < 3; w++) {
                float2 fv = __half22float2(*(const __half2*)&us[w]);
                acc[2 * w] += fv.x;
                acc[2 * w + 1] += fv.y;
            }
        }
    }
    for (; j < end; j++) {
        u32x4 u = hb[(size_t)csr_src[j]];
        unsigned int us[3] = {u[0], u[1], u[2]};
#pragma unroll
        for (int w = 0; w < 3; w++) {
            float2 fv = __half22float2(*(const __half2*)&us[w]);
            acc[2 * w] += fv.x;
            acc[2 * w + 1] += fv.y;
        }
    }
    if (!lo) {
#pragma unroll
        for (int k = 0; k < NOUT; k++) lacc[tl][k] = acc[k];
    }
    __syncthreads();
    if (!lo || !active) return;
#pragma unroll
    for (int k = 0; k < NOUT; k++) acc[k] += lacc[tl][k];
    float di = dinv[i];
    float v[NOUT];
#pragma unroll
    for (int k = 0; k < NOUT; k++) v[k] = acc[k] * di + sb[k];
    float m = -1e30f;
#pragma unroll
    for (int k = 0; k < NOUT; k++) m = fmaxf(m, v[k]);
    float se = 0.f;
#pragma unroll
    for (int k = 0; k < NOUT; k++) se += expf(v[k] - m);
    float l = logf(se);
#pragma unroll
    for (int k = 0; k < NOUT; k++) out[(size_t)i * NOUT + k] = v[k] - m - l;
}

extern "C" void kernel_launch(void* const* d_in, const int* in_sizes, int n_in,
                              void* d_out, int out_size, void* d_ws, size_t ws_size,
                              hipStream_t stream) {
    const float* x  = (const float*)d_in[0];
    const int*   ei = (const int*)d_in[1];
    const float* W1 = (const float*)d_in[2];
    const float* b1 = (const float*)d_in[3];
    const float* W2 = (const float*)d_in[4];
    const float* b2 = (const float*)d_in[5];
    float* out = (float*)d_out;

    int n  = in_sizes[0] / NFEAT_IN;   // 200000
    int ne = in_sizes[1] / 2;          // 6400000
    const int* src = ei;
    const int* dst = ei + ne;

    int nb = (n + BW - 1) >> BSHIFT;          // 391
    // arena capacity per bucket: mean + ~12 sigma headroom for uniform dst
    int cap = (ne + nb - 1) / nb + ne / (nb * 16) + 1536;

    char* base = (char*)d_ws;
    size_t off = 0;
    auto alloc = [&](size_t bytes) {
        void* p = base + off;
        off += (bytes + 63) & ~(size_t)63;
        return p;
    };
    int* bcur     = (int*)alloc(NB * 4);
    int* cnt      = (int*)alloc(NB * 4);
    int* csr_boff = (int*)alloc(NB * 4);
    unsigned int* bucketed = (unsigned int*)alloc((size_t)nb * cap * 4);
    int* csr_src  = (int*)alloc((size_t)ne * 4);
    int* node_off = (int*)alloc(((size_t)nb * BW + 1) * 4);
    float* dinv   = (float*)alloc((size_t)n * 4);
    // hs1h/hs2h overlay the arena (dead after k_sort; hs* written after)
    __half2* hs1h;
    __half2* hs2h;
    if ((size_t)nb * cap * 4 >= (size_t)n * 48) {
        hs1h = (__half2*)bucketed;
        hs2h = (__half2*)((char*)bucketed + (size_t)n * 32);
    } else {
        hs1h = (__half2*)alloc((size_t)n * 32);
        hs2h = (__half2*)alloc((size_t)n * 16);
    }

    int gp  = (ne + CHUNK - 1) / CHUNK;       // 782
    int gn  = (n + 255) / 256;
    int gn1 = (n + 63) / 64;                  // 4 threads/node for k_agg1
    int gn2 = (n + 127) / 128;                // 2 threads/node for k_agg2

    k_init_bcur<<<(NB + 255) / 256, 256, 0, stream>>>(bcur, cap);
    k_partition<<<gp, PB, 0, stream>>>(src, dst, bcur, bucketed, cap, ne);
    k_cnt_scan<<<1, 512, 0, stream>>>(bcur, cap, cnt, csr_boff, nb);
    k_sort<<<nb, 512, 0, stream>>>(bucketed, cap, cnt, csr_boff, csr_src, node_off, dinv, n, ne, nb);
    k_dense1<<<gn, 256, 0, stream>>>(x, W1, dinv, hs1h, n);
    k_agg1<<<gn1, 256, 0, stream>>>(csr_src, node_off, hs1h, b1, W2, dinv, hs2h, n);
    k_agg2<<<gn2, 256, 0, stream>>>(csr_src, node_off, hs2h, b2, dinv, out, n);
}

// Round 14
// 343.622 us; speedup vs baseline: 1.0682x; 1.0682x over previous
//
#include <hip/hip_runtime.h>
#include <hip/hip_fp16.h>

#define NFEAT_IN 21
#define NHID 16
#define NOUT 6
#define BSHIFT 9
#define BW (1 << BSHIFT)     // 512 nodes per bucket
#define NB 512               // bucket array size (supports n <= 262144)
#define PB2 512
#define EPT2 16
#define CHUNK (PB2 * EPT2)   // 8192 edges per partition block

typedef unsigned int u32x4 __attribute__((ext_vector_type(4)));

// static arenas: bucket b's region starts at b*cap
__global__ void k_init_bcur(int* __restrict__ bcur, int cap) {
    int b = blockIdx.x * blockDim.x + threadIdx.x;
    if (b < NB) bcur[b] = b * cap;
}

// LDS-local bucket sort per 8192-edge chunk, then COALESCED emission.
// Round-13 finding: halving LDS atomics was NULL — partition is
// latency-starved at 2 waves/SIMD (56.8KB LDS -> 2 blocks/CU x 4 waves).
// Fix: 512-thread blocks, same CHUNK/LDS -> 2 blocks x 8 waves = 16
// waves/CU, 4 waves/SIMD — 2x latency hiding, algorithm unchanged.
__global__ __launch_bounds__(512) void
k_partition(const int* __restrict__ src, const int* __restrict__ dst,
            int* __restrict__ bcur, unsigned int* __restrict__ bucketed,
            int cap, int ne) {
    __shared__ unsigned int ebd[CHUNK];     // (dst<<13)|rank; 0xFFFFFFFF invalid
    __shared__ unsigned short sidx[CHUNK];  // bucket-sorted pos -> chunk idx
    __shared__ int lcnt[NB], lstart[NB], lbase[NB];
    __shared__ int s[NB];
    __shared__ int sh_total;
    int t = threadIdx.x;
    long base = (long)blockIdx.x * CHUNK;
    lcnt[t] = 0;                 // PB2 == NB == 512
    __syncthreads();
    // pass 1: read dst; 1 atomic/edge captures count AND rank
#pragma unroll
    for (int k = 0; k < EPT2; k++) {
        int idx = t + k * PB2;
        long e = base + idx;
        unsigned int v = 0xFFFFFFFFu;
        if (e < ne) {
            unsigned int d = (unsigned int)dst[e];
            int r = atomicAdd(&lcnt[d >> BSHIFT], 1);
            v = (d << 13) | (unsigned int)r;
        }
        ebd[idx] = v;
    }
    __syncthreads();
    // exclusive scan of 512 bins, one per thread + reserve global
    int v = lcnt[t];
    s[t] = v;
    __syncthreads();
    for (int off = 1; off < NB; off <<= 1) {
        int tv = (t >= off) ? s[t - off] : 0;
        __syncthreads();
        s[t] += tv;
        __syncthreads();
    }
    int ex = s[t] - v;
    lstart[t] = ex;
    if (v > 0) lbase[t] = atomicAdd(&bcur[t], v);
    if (t == NB - 1) sh_total = s[NB - 1];
    __syncthreads();
    // pass 2: place each edge at its sorted slot — NO atomics
#pragma unroll
    for (int k = 0; k < EPT2; k++) {
        int idx = t + k * PB2;
        unsigned int vv = ebd[idx];
        if (vv != 0xFFFFFFFFu) {
            unsigned int d = vv >> 13;
            unsigned int r = vv & 8191u;
            sidx[lstart[d >> BSHIFT] + r] = (unsigned short)idx;
        }
    }
    __syncthreads();
    int total = sh_total;
    // pass 3: coalesced emission (consecutive j -> consecutive gpos in-run)
#pragma unroll
    for (int k = 0; k < EPT2; k++) {
        int j = t + k * PB2;
        if (j < total) {
            int idx = sidx[j];
            unsigned int d = ebd[idx] >> 13;
            int b = d >> BSHIFT;
            long gpos = (long)lbase[b] + (j - lstart[b]);
            int s_ = src[base + idx];
            if (gpos < (long)(b + 1) * cap)   // arena overflow guard (~12 sigma)
                bucketed[gpos] = ((unsigned int)s_ << BSHIFT) | (d & (BW - 1));
        }
    }
}

// counts + exclusive scan over <=512 buckets (1 block, 512 threads)
__global__ __launch_bounds__(512) void
k_cnt_scan(const int* __restrict__ bcur, int cap, int* __restrict__ cnt,
           int* __restrict__ csr_boff, int nb) {
    __shared__ int s[512];
    int t = threadIdx.x;
    int c = (t < nb) ? (bcur[t] - t * cap) : 0;
    s[t] = c;
    __syncthreads();
    for (int off = 1; off < 512; off <<= 1) {
        int tv = (t >= off) ? s[t - off] : 0;
        __syncthreads();
        s[t] += tv;
        __syncthreads();
    }
    if (t < nb) { cnt[t] = c; csr_boff[t] = s[t] - c; }
}

// Counting-sort each bucket by dst_local -> exact dst-sorted CSR.
// At the 2-LDS-atomic/edge floor — do not touch.
__global__ __launch_bounds__(512) void
k_sort(const unsigned int* __restrict__ bucketed, int cap,
       const int* __restrict__ cnt, const int* __restrict__ csr_boff,
       int* __restrict__ csr_src, int* __restrict__ node_off,
       float* __restrict__ dinv, int n, int ne, int nb) {
    __shared__ int bin[BW], sc[BW], bcur_l[BW];
    int b = blockIdx.x, t = threadIdx.x;
    bin[t] = 0;
    __syncthreads();
    size_t s0r = (size_t)b * cap;
    int c = cnt[b], s0c = csr_boff[b];
    for (int j = t; j < c; j += 512) atomicAdd(&bin[bucketed[s0r + j] & (BW - 1)], 1);
    __syncthreads();
    sc[t] = bin[t];
    __syncthreads();
    for (int off = 1; off < BW; off <<= 1) {
        int v = (t >= off) ? sc[t - off] : 0;
        __syncthreads();
        sc[t] += v;
        __syncthreads();
    }
    {
        int ex = sc[t] - bin[t];            // exclusive prefix
        bcur_l[t] = s0c + ex;
        node_off[(b << BSHIFT) + t] = s0c + ex;
        int node = (b << BSHIFT) + t;
        if (node < n) dinv[node] = rsqrtf((float)bin[t] + 1.0f);
    }
    if (b == 0 && t == 0) node_off[(size_t)nb << BSHIFT] = ne;  // sentinel
    __syncthreads();
    for (int j = t; j < c; j += 512) {
        unsigned int e = bucketed[s0r + j];
        int pos = atomicAdd(&bcur_l[e & (BW - 1)], 1);
        csr_src[pos] = (int)(e >> BSHIFT);
    }
}

// hs1h = fp16((x @ W1) * dinv[i]) — 16 halves (32B) per node
__global__ void k_dense1(const float* __restrict__ x, const float* __restrict__ W1,
                         const float* __restrict__ dinv, __half2* __restrict__ hs1h, int n) {
    __shared__ float sW[NFEAT_IN * NHID];
    for (int t = threadIdx.x; t < NFEAT_IN * NHID; t += blockDim.x) sW[t] = W1[t];
    __syncthreads();
    int i = blockIdx.x * blockDim.x + threadIdx.x;
    if (i >= n) return;
    float xi[NFEAT_IN];
#pragma unroll
    for (int k = 0; k < NFEAT_IN; k++) xi[k] = x[(size_t)i * NFEAT_IN + k];
    float di = dinv[i];
    float r[NHID];
#pragma unroll
    for (int j = 0; j < NHID; j++) {
        float acc = 0.f;
#pragma unroll
        for (int k = 0; k < NFEAT_IN; k++) acc += xi[k] * sW[k * NHID + j];
        r[j] = acc * di;
    }
    __half2* hp = hs1h + (size_t)i * 8;
#pragma unroll
    for (int q = 0; q < 8; q++) hp[q] = __floats2half2_rn(r[2 * q], r[2 * q + 1]);
}

__device__ __forceinline__ void addh16(float* acc, u32x4 u0, u32x4 u1) {
    unsigned int us[8] = {u0[0], u0[1], u0[2], u0[3], u1[0], u1[1], u1[2], u1[3]};
#pragma unroll
    for (int q = 0; q < 8; q++) {
        float2 f = __half22float2(*(const __half2*)&us[q]);
        acc[2 * q] += f.x;
        acc[2 * q + 1] += f.y;
    }
}

// CSR aggregate layer1 + relu + dense2 — 4 THREADS PER NODE.
// At the ~3.05 TB/s sustained random-line gather limit — do not touch.
__global__ __launch_bounds__(256) void
k_agg1(const int* __restrict__ csr_src, const int* __restrict__ node_off,
       const __half2* __restrict__ hs1h, const float* __restrict__ b1,
       const float* __restrict__ W2, const float* __restrict__ dinv,
       __half2* __restrict__ hs2h, int n) {
    __shared__ float sW[NHID * NOUT];
    __shared__ float sb[NHID];
    __shared__ float lacc[3][64][NHID + 1];
    int t = threadIdx.x;
    if (t < NHID * NOUT) sW[t] = W2[t];
    if (t < NHID) sb[t] = b1[t];
    int tl = t & 63;
    int seg = t >> 6;            // 0..3
    int i = (blockIdx.x << 6) + tl;
    bool active = (i < n);
    int beg = 0, end = 0;
    if (active) {
        int b0 = node_off[i], e0 = node_off[i + 1];
        int len = e0 - b0;
        beg = b0 + (len * seg) / 4;
        end = b0 + (len * (seg + 1)) / 4;
    }
    const u32x4* hb = (const u32x4*)hs1h;
    float acc[NHID];
#pragma unroll
    for (int k = 0; k < NHID; k++) acc[k] = 0.f;
    if (active && seg == 0) {   // self contribution (self-loop: A+I)
        u32x4 u0 = hb[(size_t)i * 2], u1 = hb[(size_t)i * 2 + 1];
        unsigned int us[8] = {u0[0], u0[1], u0[2], u0[3], u1[0], u1[1], u1[2], u1[3]};
#pragma unroll
        for (int q = 0; q < 8; q++) {
            float2 f = __half22float2(*(const __half2*)&us[q]);
            acc[2 * q] = f.x;
            acc[2 * q + 1] = f.y;
        }
    }
    int j = beg;
    for (; j + 4 <= end; j += 4) {
        int s0_ = csr_src[j], s1_ = csr_src[j + 1];
        int s2_ = csr_src[j + 2], s3_ = csr_src[j + 3];
        u32x4 a0 = hb[(size_t)s0_ * 2], a1 = hb[(size_t)s0_ * 2 + 1];
        u32x4 b0 = hb[(size_t)s1_ * 2], b1v = hb[(size_t)s1_ * 2 + 1];
        u32x4 c0 = hb[(size_t)s2_ * 2], c1 = hb[(size_t)s2_ * 2 + 1];
        u32x4 d0 = hb[(size_t)s3_ * 2], d1 = hb[(size_t)s3_ * 2 + 1];
        addh16(acc, a0, a1);
        addh16(acc, b0, b1v);
        addh16(acc, c0, c1);
        addh16(acc, d0, d1);
    }
    for (; j < end; j++) {
        int s_ = csr_src[j];
        addh16(acc, hb[(size_t)s_ * 2], hb[(size_t)s_ * 2 + 1]);
    }
    if (seg != 0) {
#pragma unroll
        for (int k = 0; k < NHID; k++) lacc[seg - 1][tl][k] = acc[k];
    }
    __syncthreads();
    if (seg != 0 || !active) return;
#pragma unroll
    for (int k = 0; k < NHID; k++)
        acc[k] += lacc[0][tl][k] + lacc[1][tl][k] + lacc[2][tl][k];
    float di = dinv[i];
    float z[NHID];
#pragma unroll
    for (int k = 0; k < NHID; k++) z[k] = fmaxf(acc[k] * di + sb[k], 0.0f);
    float h[8];
#pragma unroll
    for (int kk = 0; kk < NOUT; kk++) {
        float s = 0.f;
#pragma unroll
        for (int jj = 0; jj < NHID; jj++) s += z[jj] * sW[jj * NOUT + kk];
        h[kk] = s * di;
    }
    h[6] = 0.f; h[7] = 0.f;
    __half2* op = hs2h + (size_t)i * 4;
#pragma unroll
    for (int q = 0; q < 4; q++) op[q] = __floats2half2_rn(h[2 * q], h[2 * q + 1]);
}

// CSR aggregate layer2 + bias + log_softmax — 2 THREADS PER NODE
__global__ __launch_bounds__(256) void
k_agg2(const int* __restrict__ csr_src, const int* __restrict__ node_off,
       const __half2* __restrict__ hs2h, const float* __restrict__ b2,
       const float* __restrict__ dinv, float* __restrict__ out, int n) {
    __shared__ float sb[NOUT];
    __shared__ float lacc[128][NOUT + 1];
    int t = threadIdx.x;
    if (t < NOUT) sb[t] = b2[t];
    int tl = t & 127;
    bool lo = (t < 128);
    int i = (blockIdx.x << 7) + tl;
    bool active = (i < n);
    int beg = 0, end = 0;
    if (active) {
        int b0 = node_off[i], e0 = node_off[i + 1];
        int h = (e0 - b0 + 1) >> 1;
        beg = lo ? b0 : b0 + h;
        end = lo ? b0 + h : e0;
    }
    const u32x4* hb = (const u32x4*)hs2h;
    float acc[NOUT];
#pragma unroll
    for (int k = 0; k < NOUT; k++) acc[k] = 0.f;
    if (active && lo) {   // self
        u32x4 u = hb[(size_t)i];
        unsigned int us[3] = {u[0], u[1], u[2]};
#pragma unroll
        for (int q = 0; q < 3; q++) {
            float2 f = __half22float2(*(const __half2*)&us[q]);
            acc[2 * q] = f.x;
            acc[2 * q + 1] = f.y;
        }
    }
    int j = beg;
    for (; j + 8 <= end; j += 8) {
        int sid[8];
#pragma unroll
        for (int q = 0; q < 8; q++) sid[q] = csr_src[j + q];
        u32x4 u[8];
#pragma unroll
        for (int q = 0; q < 8; q++) u[q] = hb[(size_t)sid[q]];
#pragma unroll
        for (int q = 0; q < 8; q++) {
            unsigned int us[3] = {u[q][0], u[q][1], u[q][2]};
#pragma unroll
            for (int w = 0; w < 3; w++) {
                float2 fv = __half22float2(*(const __half2*)&us[w]);
                acc[2 * w] += fv.x;
                acc[2 * w + 1] += fv.y;
            }
        }
    }
    for (; j < end; j++) {
        u32x4 u = hb[(size_t)csr_src[j]];
        unsigned int us[3] = {u[0], u[1], u[2]};
#pragma unroll
        for (int w = 0; w < 3; w++) {
            float2 fv = __half22float2(*(const __half2*)&us[w]);
            acc[2 * w] += fv.x;
            acc[2 * w + 1] += fv.y;
        }
    }
    if (!lo) {
#pragma unroll
        for (int k = 0; k < NOUT; k++) lacc[tl][k] = acc[k];
    }
    __syncthreads();
    if (!lo || !active) return;
#pragma unroll
    for (int k = 0; k < NOUT; k++) acc[k] += lacc[tl][k];
    float di = dinv[i];
    float v[NOUT];
#pragma unroll
    for (int k = 0; k < NOUT; k++) v[k] = acc[k] * di + sb[k];
    float m = -1e30f;
#pragma unroll
    for (int k = 0; k < NOUT; k++) m = fmaxf(m, v[k]);
    float se = 0.f;
#pragma unroll
    for (int k = 0; k < NOUT; k++) se += expf(v[k] - m);
    float l = logf(se);
#pragma unroll
    for (int k = 0; k < NOUT; k++) out[(size_t)i * NOUT + k] = v[k] - m - l;
}

extern "C" void kernel_launch(void* const* d_in, const int* in_sizes, int n_in,
                              void* d_out, int out_size, void* d_ws, size_t ws_size,
                              hipStream_t stream) {
    const float* x  = (const float*)d_in[0];
    const int*   ei = (const int*)d_in[1];
    const float* W1 = (const float*)d_in[2];
    const float* b1 = (const float*)d_in[3];
    const float* W2 = (const float*)d_in[4];
    const float* b2 = (const float*)d_in[5];
    float* out = (float*)d_out;

    int n  = in_sizes[0] / NFEAT_IN;   // 200000
    int ne = in_sizes[1] / 2;          // 6400000
    const int* src = ei;
    const int* dst = ei + ne;

    int nb = (n + BW - 1) >> BSHIFT;          // 391
    // arena capacity per bucket: mean + ~12 sigma headroom for uniform dst
    int cap = (ne + nb - 1) / nb + ne / (nb * 16) + 1536;

    char* base = (char*)d_ws;
    size_t off = 0;
    auto alloc = [&](size_t bytes) {
        void* p = base + off;
        off += (bytes + 63) & ~(size_t)63;
        return p;
    };
    int* bcur     = (int*)alloc(NB * 4);
    int* cnt      = (int*)alloc(NB * 4);
    int* csr_boff = (int*)alloc(NB * 4);
    unsigned int* bucketed = (unsigned int*)alloc((size_t)nb * cap * 4);
    int* csr_src  = (int*)alloc((size_t)ne * 4);
    int* node_off = (int*)alloc(((size_t)nb * BW + 1) * 4);
    float* dinv   = (float*)alloc((size_t)n * 4);
    // hs1h/hs2h overlay the arena (dead after k_sort; hs* written after)
    __half2* hs1h;
    __half2* hs2h;
    if ((size_t)nb * cap * 4 >= (size_t)n * 48) {
        hs1h = (__half2*)bucketed;
        hs2h = (__half2*)((char*)bucketed + (size_t)n * 32);
    } else {
        hs1h = (__half2*)alloc((size_t)n * 32);
        hs2h = (__half2*)alloc((size_t)n * 16);
    }

    int gp  = (ne + CHUNK - 1) / CHUNK;       // 782
    int gn  = (n + 255) / 256;
    int gn1 = (n + 63) / 64;                  // 4 threads/node for k_agg1
    int gn2 = (n + 127) / 128;                // 2 threads/node for k_agg2

    k_init_bcur<<<(NB + 255) / 256, 256, 0, stream>>>(bcur, cap);
    k_partition<<<gp, PB2, 0, stream>>>(src, dst, bcur, bucketed, cap, ne);
    k_cnt_scan<<<1, 512, 0, stream>>>(bcur, cap, cnt, csr_boff, nb);
    k_sort<<<nb, 512, 0, stream>>>(bucketed, cap, cnt, csr_boff, csr_src, node_off, dinv, n, ne, nb);
    k_dense1<<<gn, 256, 0, stream>>>(x, W1, dinv, hs1h, n);
    k_agg1<<<gn1, 256, 0, stream>>>(csr_src, node_off, hs1h, b1, W2, dinv, hs2h, n);
    k_agg2<<<gn2, 256, 0, stream>>>(csr_src, node_off, hs2h, b2, dinv, out, n);
}